// Round 1
// baseline (8820.249 us; speedup 1.0000x reference)
//
#include <hip/hip_runtime.h>
#include <math.h>

#define G 20000
#define E_EDGES 640000
#define HID 64
#define NHEAD 4
#define BATCH 128
#define PD 600
#define NEG 0.2f
#define MAXE 1024

__device__ __forceinline__ float sigmoidf_(float x){ return 1.0f/(1.0f+__expf(-x)); }
__device__ __forceinline__ float leakyf_(float x){ return x>=0.f ? x : NEG*x; }

// ---------- Stage 1: hc = [x | gene_embed[pos]] @ [conv1_W | lin1_W]  (G x 320) ----------
__global__ void k_hc(const float* __restrict__ x, const int* __restrict__ pos,
                     const float* __restrict__ ge, const float* __restrict__ Wc,
                     const float* __restrict__ Wl, float* __restrict__ hc)
{
    int i = blockIdx.x;
    int t = threadIdx.x; // 320 threads
    __shared__ float xc[65];
    if (t < 65) xc[t] = (t == 0) ? x[i] : ge[pos[i]*HID + (t-1)];
    __syncthreads();
    float acc = 0.f;
    if (t < 256) {
        for (int k = 0; k < 65; ++k) acc += xc[k] * Wc[k*256 + t];
    } else {
        int c = t - 256;
        for (int k = 0; k < 65; ++k) acc += xc[k] * Wl[k*64 + c];
    }
    hc[i*320 + t] = acc;
}

// ---------- e_src / e_dst for conv1: dot(h[i,h,:], a[h,:]) ----------
__global__ void k_attn_coef(const float* __restrict__ hc, const float* __restrict__ as_,
                            const float* __restrict__ ad_, float* __restrict__ es,
                            float* __restrict__ ed)
{
    int i = blockIdx.x; int t = threadIdx.x; // 256
    float hv = hc[i*320 + t];
    float v1 = hv * as_[t];
    float v2 = hv * ad_[t];
    for (int m = 32; m; m >>= 1) { v1 += __shfl_xor(v1, m); v2 += __shfl_xor(v2, m); }
    if ((t & 63) == 0) { int h = t >> 6; es[i*4+h] = v1; ed[i*4+h] = v2; }
}

// ---------- CSR build ----------
__global__ void k_hist(const int* __restrict__ ei, int* __restrict__ cnt){
    int e = blockIdx.x*blockDim.x + threadIdx.x;
    if (e < E_EDGES) atomicAdd(&cnt[ei[E_EDGES + e]], 1);
}
__global__ void k_scan(const int* __restrict__ cnt, int* __restrict__ offs){
    __shared__ int buf[1024];
    __shared__ int carry;
    int t = threadIdx.x;
    if (t == 0){ carry = 0; offs[0] = 0; }
    __syncthreads();
    for (int base = 0; base < G; base += 1024){
        int v = (base + t < G) ? cnt[base + t] : 0;
        buf[t] = v; __syncthreads();
        for (int off = 1; off < 1024; off <<= 1){
            int add = (t >= off) ? buf[t - off] : 0;
            __syncthreads();
            buf[t] += add;
            __syncthreads();
        }
        if (base + t < G) offs[base + t + 1] = carry + buf[t];
        __syncthreads();
        if (t == 0) carry += buf[1023];
        __syncthreads();
    }
}
__global__ void k_cursor(const int* __restrict__ offs, int* __restrict__ cur){
    int i = blockIdx.x*blockDim.x + threadIdx.x;
    if (i < G) cur[i] = offs[i];
}
__global__ void k_scatter(const int* __restrict__ ei, int* __restrict__ cur, int* __restrict__ csr){
    int e = blockIdx.x*blockDim.x + threadIdx.x;
    if (e < E_EDGES){
        int d = ei[E_EDGES + e];
        int p = atomicAdd(&cur[d], 1);
        csr[p] = ei[e];
    }
}

// ---------- GAT1 apply: per-dst softmax + SpMM + head-mean + lin1 + sigmoid ----------
__global__ void k_gat1(const float* __restrict__ hc, const float* __restrict__ es,
                       const float* __restrict__ ed, const int* __restrict__ offs,
                       const int* __restrict__ csr, const float* __restrict__ bc1,
                       const float* __restrict__ bl1, float* __restrict__ h1)
{
    int d = blockIdx.x; int t = threadIdx.x; // 256
    __shared__ float cache[MAXE*4];
    __shared__ int   ssrc[MAXE];
    __shared__ float red[256];
    __shared__ float bc[8];
    int o = offs[d];
    int deg = offs[d+1] - o;
    int total = deg + 1;              // + self loop
    if (total > MAXE) total = MAXE;   // never in practice (lambda=32)
    float edst[4];
    #pragma unroll
    for (int h = 0; h < 4; ++h) edst[h] = ed[d*4+h];
    float lmax[4] = {-1e30f,-1e30f,-1e30f,-1e30f};
    for (int idx = t; idx < total; idx += 256){
        int s = (idx < deg) ? csr[o + idx] : d;
        ssrc[idx] = s;
        #pragma unroll
        for (int h = 0; h < 4; ++h){
            float e = leakyf_(es[s*4+h] + edst[h]);
            cache[idx*4+h] = e;
            lmax[h] = fmaxf(lmax[h], e);
        }
    }
    __syncthreads();
    #pragma unroll
    for (int h = 0; h < 4; ++h){
        red[t] = lmax[h]; __syncthreads();
        for (int s2 = 128; s2; s2 >>= 1){ if (t < s2) red[t] = fmaxf(red[t], red[t+s2]); __syncthreads(); }
        if (t == 0) bc[h] = red[0];
        __syncthreads();
    }
    float m0 = bc[0], m1 = bc[1], m2 = bc[2], m3 = bc[3];
    float lsum[4] = {0.f,0.f,0.f,0.f};
    for (int idx = t; idx < total; idx += 256){
        float e0 = __expf(cache[idx*4+0] - m0); cache[idx*4+0] = e0; lsum[0] += e0;
        float e1 = __expf(cache[idx*4+1] - m1); cache[idx*4+1] = e1; lsum[1] += e1;
        float e2 = __expf(cache[idx*4+2] - m2); cache[idx*4+2] = e2; lsum[2] += e2;
        float e3 = __expf(cache[idx*4+3] - m3); cache[idx*4+3] = e3; lsum[3] += e3;
    }
    __syncthreads();
    #pragma unroll
    for (int h = 0; h < 4; ++h){
        red[t] = lsum[h]; __syncthreads();
        for (int s2 = 128; s2; s2 >>= 1){ if (t < s2) red[t] += red[t+s2]; __syncthreads(); }
        if (t == 0) bc[4+h] = 1.0f / red[0];
        __syncthreads();
    }
    int h = t >> 6, c = t & 63;
    float inv = bc[4+h];
    float acc = 0.f;
    for (int idx = 0; idx < total; ++idx){
        int s = ssrc[idx];
        float alpha = cache[idx*4+h] * inv;
        acc += alpha * hc[s*320 + h*64 + c];
    }
    red[t] = acc;
    __syncthreads();
    if (t < 64){
        float sum = red[t] + red[64+t] + red[128+t] + red[192+t];
        float val = 0.25f*sum + bc1[t] + hc[d*320 + 256 + t] + bl1[t];
        h1[d*64 + t] = sigmoidf_(val);
    }
}

// ---------- conv2 prep: hh2 = h1@conv2_W (Gx4), attn coefs, lin2 ----------
__global__ void k_conv2prep(const float* __restrict__ h1, const float* __restrict__ W2c,
                            const float* __restrict__ as2, const float* __restrict__ ad2,
                            const float* __restrict__ Wl2, float* __restrict__ hh2,
                            float* __restrict__ es2, float* __restrict__ ed2,
                            float* __restrict__ lv)
{
    int i = blockIdx.x; int k = threadIdx.x; // 64
    float hv = h1[i*64 + k];
    #pragma unroll
    for (int j = 0; j < 4; ++j){
        float v = hv * W2c[k*4 + j];
        for (int m = 32; m; m >>= 1) v += __shfl_xor(v, m);
        if (k == 0){ hh2[i*4+j] = v; es2[i*4+j] = v*as2[j]; ed2[i*4+j] = v*ad2[j]; }
    }
    float v = hv * Wl2[k];
    for (int m = 32; m; m >>= 1) v += __shfl_xor(v, m);
    if (k == 0) lv[i] = v;
}

// ---------- GAT2 apply (C=1): fused softmax + weighted sum + sigmoid -> feat ----------
__global__ void k_gat2(const float* __restrict__ hh2, const float* __restrict__ es2,
                       const float* __restrict__ ed2, const int* __restrict__ offs,
                       const int* __restrict__ csr, const float* __restrict__ lv,
                       const float* __restrict__ bc2, const float* __restrict__ bl2,
                       float* __restrict__ feat)
{
    int d = blockIdx.x; int j = threadIdx.x; // 64
    int o = offs[d];
    int deg = offs[d+1] - o;
    int total = deg + 1;
    float edst[4];
    #pragma unroll
    for (int h = 0; h < 4; ++h) edst[h] = ed2[d*4+h];
    float lmax[4] = {-1e30f,-1e30f,-1e30f,-1e30f};
    for (int idx = j; idx < total; idx += 64){
        int s = (idx < deg) ? csr[o + idx] : d;
        #pragma unroll
        for (int h = 0; h < 4; ++h)
            lmax[h] = fmaxf(lmax[h], leakyf_(es2[s*4+h] + edst[h]));
    }
    #pragma unroll
    for (int h = 0; h < 4; ++h)
        for (int m = 32; m; m >>= 1) lmax[h] = fmaxf(lmax[h], __shfl_xor(lmax[h], m));
    float lsum[4] = {0.f,0.f,0.f,0.f};
    float lnum[4] = {0.f,0.f,0.f,0.f};
    for (int idx = j; idx < total; idx += 64){
        int s = (idx < deg) ? csr[o + idx] : d;
        #pragma unroll
        for (int h = 0; h < 4; ++h){
            float e  = leakyf_(es2[s*4+h] + edst[h]);
            float ex = __expf(e - lmax[h]);
            lsum[h] += ex;
            lnum[h] += ex * hh2[s*4+h];
        }
    }
    #pragma unroll
    for (int h = 0; h < 4; ++h){
        for (int m = 32; m; m >>= 1){ lsum[h] += __shfl_xor(lsum[h], m); lnum[h] += __shfl_xor(lnum[h], m); }
    }
    if (j == 0){
        float sum = 0.f;
        #pragma unroll
        for (int h = 0; h < 4; ++h) sum += lnum[h] / lsum[h];
        feat[d] = sigmoidf_(0.25f*sum + bc2[0] + lv[d] + bl2[0]);
    }
}

// ---------- pert MLP: p = sigmoid(pert@W1+b1)@W2+b2  (128x64) ----------
__global__ void k_pert(const float* __restrict__ pert, const float* __restrict__ W1,
                       const float* __restrict__ b1, const float* __restrict__ W2,
                       const float* __restrict__ b2, float* __restrict__ p)
{
    int r = blockIdx.x; int t = threadIdx.x; // 128
    __shared__ float hid[128];
    float acc = 0.f;
    for (int k = 0; k < PD; ++k) acc += pert[r*PD + k] * W1[k*128 + t];
    hid[t] = sigmoidf_(acc + b1[t]);
    __syncthreads();
    if (t < 64){
        float a2 = 0.f;
        for (int k = 0; k < 128; ++k) a2 += hid[k] * W2[k*64 + t];
        p[r*64 + t] = a2 + b2[t];
    }
}

// ---------- pred GEMM1: hpre += inp @ pred_W1 (K-split x16, atomics) ----------
#define KCHUNK 1254
__global__ void k_gemm1(const float* __restrict__ ctrl, const float* __restrict__ feat,
                        const float* __restrict__ p, const float* __restrict__ W1,
                        float* __restrict__ hpre)
{
    int tx = threadIdx.x & 63, ty = threadIdx.x >> 6;
    int col = blockIdx.x*64 + tx;
    int kbeg = blockIdx.y*KCHUNK, kend = kbeg + KCHUNK;
    __shared__ float a[128*8];
    float acc[32];
    #pragma unroll
    for (int i = 0; i < 32; ++i) acc[i] = 0.f;
    for (int k0 = kbeg; k0 < kend; k0 += 8){
        for (int l = threadIdx.x; l < 1024; l += 256){
            int row = l >> 3, kk = l & 7, kg = k0 + kk;
            float v = 0.f;
            if (kg < kend)
                v = (kg < 20000) ? (ctrl[row*20000 + kg] + feat[kg]) : p[row*64 + (kg - 20000)];
            a[l] = v;
        }
        __syncthreads();
        #pragma unroll
        for (int kk = 0; kk < 8; ++kk){
            int kg = k0 + kk;
            float w = (kg < kend) ? W1[kg*1024 + col] : 0.f;
            #pragma unroll
            for (int i = 0; i < 32; ++i) acc[i] += a[(ty*32 + i)*8 + kk] * w;
        }
        __syncthreads();
    }
    #pragma unroll
    for (int i = 0; i < 32; ++i) atomicAdd(&hpre[(ty*32 + i)*1024 + col], acc[i]);
}

__global__ void k_sig(float* __restrict__ hid, const float* __restrict__ b){
    int i = blockIdx.x*blockDim.x + threadIdx.x;
    if (i < BATCH*1024) hid[i] = sigmoidf_(hid[i] + b[i & 1023]);
}

// ---------- pred GEMM2: out = hidden @ pred_W2 + b2 ----------
__global__ void k_gemm2(const float* __restrict__ hid, const float* __restrict__ W2,
                        const float* __restrict__ b2, float* __restrict__ out)
{
    int tx = threadIdx.x & 63, ty = threadIdx.x >> 6;
    int col = blockIdx.x*64 + tx;
    bool valid = col < 20000;
    __shared__ float a[128*8];
    float acc[32];
    #pragma unroll
    for (int i = 0; i < 32; ++i) acc[i] = 0.f;
    for (int k0 = 0; k0 < 1024; k0 += 8){
        for (int l = threadIdx.x; l < 1024; l += 256){
            int row = l >> 3, kk = l & 7;
            a[l] = hid[row*1024 + k0 + kk];
        }
        __syncthreads();
        #pragma unroll
        for (int kk = 0; kk < 8; ++kk){
            float w = valid ? W2[(k0 + kk)*20000 + col] : 0.f;
            #pragma unroll
            for (int i = 0; i < 32; ++i) acc[i] += a[(ty*32 + i)*8 + kk] * w;
        }
        __syncthreads();
    }
    if (valid){
        float bb = b2[col];
        #pragma unroll
        for (int i = 0; i < 32; ++i) out[(ty*32 + i)*20000 + col] = acc[i] + bb;
    }
}

extern "C" void kernel_launch(void* const* d_in, const int* in_sizes, int n_in,
                              void* d_out, int out_size, void* d_ws, size_t ws_size,
                              hipStream_t stream)
{
    const float* x    = (const float*)d_in[0];
    const int*   ei   = (const int*)  d_in[1];
    const int*   pos  = (const int*)  d_in[2];
    const float* ctrl = (const float*)d_in[3];
    const float* pert = (const float*)d_in[4];
    const float* ge   = (const float*)d_in[5];
    const float* c1W  = (const float*)d_in[6];
    const float* c1as = (const float*)d_in[7];
    const float* c1ad = (const float*)d_in[8];
    const float* c1b  = (const float*)d_in[9];
    const float* l1W  = (const float*)d_in[10];
    const float* l1b  = (const float*)d_in[11];
    const float* c2W  = (const float*)d_in[12];
    const float* c2as = (const float*)d_in[13];
    const float* c2ad = (const float*)d_in[14];
    const float* c2b  = (const float*)d_in[15];
    const float* l2W  = (const float*)d_in[16];
    const float* l2b  = (const float*)d_in[17];
    const float* pW1  = (const float*)d_in[18];
    const float* pb1  = (const float*)d_in[19];
    const float* pW2  = (const float*)d_in[20];
    const float* pb2  = (const float*)d_in[21];
    const float* prW1 = (const float*)d_in[22];
    const float* prb1 = (const float*)d_in[23];
    const float* prW2 = (const float*)d_in[24];
    const float* prb2 = (const float*)d_in[25];
    float* out = (float*)d_out;

    char* ws = (char*)d_ws;
    size_t off = 0;
    auto alloc = [&](size_t bytes)->void*{
        void* pp = ws + off;
        off += (bytes + 255) & ~(size_t)255;
        return pp;
    };
    float* hc1  = (float*)alloc((size_t)G*320*4);
    float* h1   = (float*)alloc((size_t)G*64*4);
    float* es1  = (float*)alloc((size_t)G*4*4);
    float* ed1  = (float*)alloc((size_t)G*4*4);
    float* hh2  = (float*)alloc((size_t)G*4*4);
    float* es2  = (float*)alloc((size_t)G*4*4);
    float* ed2  = (float*)alloc((size_t)G*4*4);
    float* lv   = (float*)alloc((size_t)G*4);
    float* feat = (float*)alloc((size_t)G*4);
    float* pm   = (float*)alloc((size_t)BATCH*64*4);
    float* hpre = (float*)alloc((size_t)BATCH*1024*4);
    int*   cnt  = (int*)alloc((size_t)G*4);
    int*   offs = (int*)alloc((size_t)(G+1)*4);
    int*   cur  = (int*)alloc((size_t)G*4);
    int*   csr  = (int*)alloc((size_t)E_EDGES*4);

    hipMemsetAsync(cnt, 0, (size_t)G*4, stream);
    hipMemsetAsync(hpre, 0, (size_t)BATCH*1024*4, stream);

    k_hist   <<<(E_EDGES+255)/256, 256, 0, stream>>>(ei, cnt);
    k_scan   <<<1, 1024, 0, stream>>>(cnt, offs);
    k_cursor <<<(G+255)/256, 256, 0, stream>>>(offs, cur);
    k_scatter<<<(E_EDGES+255)/256, 256, 0, stream>>>(ei, cur, csr);

    k_hc       <<<G, 320, 0, stream>>>(x, pos, ge, c1W, l1W, hc1);
    k_attn_coef<<<G, 256, 0, stream>>>(hc1, c1as, c1ad, es1, ed1);
    k_gat1     <<<G, 256, 0, stream>>>(hc1, es1, ed1, offs, csr, c1b, l1b, h1);
    k_conv2prep<<<G, 64, 0, stream>>>(h1, c2W, c2as, c2ad, l2W, hh2, es2, ed2, lv);
    k_gat2     <<<G, 64, 0, stream>>>(hh2, es2, ed2, offs, csr, lv, c2b, l2b, feat);
    k_pert     <<<BATCH, 128, 0, stream>>>(pert, pW1, pb1, pW2, pb2, pm);

    dim3 g1(16, 16);
    k_gemm1<<<g1, 256, 0, stream>>>(ctrl, feat, pm, prW1, hpre);
    k_sig  <<<(BATCH*1024+255)/256, 256, 0, stream>>>(hpre, prb1);
    k_gemm2<<<(20000+63)/64, 256, 0, stream>>>(hpre, prW2, prb2, out);
}

// Round 2
// 6973.876 us; speedup vs baseline: 1.2648x; 1.2648x over previous
//
#include <hip/hip_runtime.h>
#include <math.h>

#define G 20000
#define E_EDGES 640000
#define HID 64
#define NHEAD 4
#define BATCH 128
#define PD 600
#define NEG 0.2f
#define MAXE 1024
#define KSPLIT 33
#define KCH 608    // 33*608 = 20064, 608 % 8 == 0

__device__ __forceinline__ float sigmoidf_(float x){ return 1.0f/(1.0f+__expf(-x)); }
__device__ __forceinline__ float leakyf_(float x){ return x>=0.f ? x : NEG*x; }

// ---------- Stage 1: hc = [x | gene_embed[pos]] @ [conv1_W | lin1_W]  (G x 320) ----------
__global__ void k_hc(const float* __restrict__ x, const int* __restrict__ pos,
                     const float* __restrict__ ge, const float* __restrict__ Wc,
                     const float* __restrict__ Wl, float* __restrict__ hc)
{
    int i = blockIdx.x;
    int t = threadIdx.x; // 320 threads
    __shared__ float xc[65];
    if (t < 65) xc[t] = (t == 0) ? x[i] : ge[pos[i]*HID + (t-1)];
    __syncthreads();
    float acc = 0.f;
    if (t < 256) {
        for (int k = 0; k < 65; ++k) acc += xc[k] * Wc[k*256 + t];
    } else {
        int c = t - 256;
        for (int k = 0; k < 65; ++k) acc += xc[k] * Wl[k*64 + c];
    }
    hc[i*320 + t] = acc;
}

// ---------- e_src / e_dst for conv1 ----------
__global__ void k_attn_coef(const float* __restrict__ hc, const float* __restrict__ as_,
                            const float* __restrict__ ad_, float* __restrict__ es,
                            float* __restrict__ ed)
{
    int i = blockIdx.x; int t = threadIdx.x; // 256
    float hv = hc[i*320 + t];
    float v1 = hv * as_[t];
    float v2 = hv * ad_[t];
    for (int m = 32; m; m >>= 1) { v1 += __shfl_xor(v1, m); v2 += __shfl_xor(v2, m); }
    if ((t & 63) == 0) { int h = t >> 6; es[i*4+h] = v1; ed[i*4+h] = v2; }
}

// ---------- CSR build (int atomics are native HW instructions) ----------
__global__ void k_hist(const int* __restrict__ ei, int* __restrict__ cnt){
    int e = blockIdx.x*blockDim.x + threadIdx.x;
    if (e < E_EDGES) atomicAdd(&cnt[ei[E_EDGES + e]], 1);
}
__global__ void k_scan(const int* __restrict__ cnt, int* __restrict__ offs){
    __shared__ int buf[1024];
    __shared__ int carry;
    int t = threadIdx.x;
    if (t == 0){ carry = 0; offs[0] = 0; }
    __syncthreads();
    for (int base = 0; base < G; base += 1024){
        int v = (base + t < G) ? cnt[base + t] : 0;
        buf[t] = v; __syncthreads();
        for (int off = 1; off < 1024; off <<= 1){
            int add = (t >= off) ? buf[t - off] : 0;
            __syncthreads();
            buf[t] += add;
            __syncthreads();
        }
        if (base + t < G) offs[base + t + 1] = carry + buf[t];
        __syncthreads();
        if (t == 0) carry += buf[1023];
        __syncthreads();
    }
}
__global__ void k_cursor(const int* __restrict__ offs, int* __restrict__ cur){
    int i = blockIdx.x*blockDim.x + threadIdx.x;
    if (i < G) cur[i] = offs[i];
}
__global__ void k_scatter(const int* __restrict__ ei, int* __restrict__ cur, int* __restrict__ csr){
    int e = blockIdx.x*blockDim.x + threadIdx.x;
    if (e < E_EDGES){
        int d = ei[E_EDGES + e];
        int p = atomicAdd(&cur[d], 1);
        csr[p] = ei[e];
    }
}

// ---------- GAT1 apply ----------
__global__ void k_gat1(const float* __restrict__ hc, const float* __restrict__ es,
                       const float* __restrict__ ed, const int* __restrict__ offs,
                       const int* __restrict__ csr, const float* __restrict__ bc1,
                       const float* __restrict__ bl1, float* __restrict__ h1)
{
    int d = blockIdx.x; int t = threadIdx.x; // 256
    __shared__ float cache[MAXE*4];
    __shared__ int   ssrc[MAXE];
    __shared__ float red[256];
    __shared__ float bc[8];
    int o = offs[d];
    int deg = offs[d+1] - o;
    int total = deg + 1;              // + self loop
    if (total > MAXE) total = MAXE;
    float edst[4];
    #pragma unroll
    for (int h = 0; h < 4; ++h) edst[h] = ed[d*4+h];
    float lmax[4] = {-1e30f,-1e30f,-1e30f,-1e30f};
    for (int idx = t; idx < total; idx += 256){
        int s = (idx < deg) ? csr[o + idx] : d;
        ssrc[idx] = s;
        #pragma unroll
        for (int h = 0; h < 4; ++h){
            float e = leakyf_(es[s*4+h] + edst[h]);
            cache[idx*4+h] = e;
            lmax[h] = fmaxf(lmax[h], e);
        }
    }
    __syncthreads();
    #pragma unroll
    for (int h = 0; h < 4; ++h){
        red[t] = lmax[h]; __syncthreads();
        for (int s2 = 128; s2; s2 >>= 1){ if (t < s2) red[t] = fmaxf(red[t], red[t+s2]); __syncthreads(); }
        if (t == 0) bc[h] = red[0];
        __syncthreads();
    }
    float m0 = bc[0], m1 = bc[1], m2 = bc[2], m3 = bc[3];
    float lsum[4] = {0.f,0.f,0.f,0.f};
    for (int idx = t; idx < total; idx += 256){
        float e0 = __expf(cache[idx*4+0] - m0); cache[idx*4+0] = e0; lsum[0] += e0;
        float e1 = __expf(cache[idx*4+1] - m1); cache[idx*4+1] = e1; lsum[1] += e1;
        float e2 = __expf(cache[idx*4+2] - m2); cache[idx*4+2] = e2; lsum[2] += e2;
        float e3 = __expf(cache[idx*4+3] - m3); cache[idx*4+3] = e3; lsum[3] += e3;
    }
    __syncthreads();
    #pragma unroll
    for (int h = 0; h < 4; ++h){
        red[t] = lsum[h]; __syncthreads();
        for (int s2 = 128; s2; s2 >>= 1){ if (t < s2) red[t] += red[t+s2]; __syncthreads(); }
        if (t == 0) bc[4+h] = 1.0f / red[0];
        __syncthreads();
    }
    int h = t >> 6, c = t & 63;
    float inv = bc[4+h];
    float acc = 0.f;
    for (int idx = 0; idx < total; ++idx){
        int s = ssrc[idx];
        float alpha = cache[idx*4+h] * inv;
        acc += alpha * hc[s*320 + h*64 + c];
    }
    red[t] = acc;
    __syncthreads();
    if (t < 64){
        float sum = red[t] + red[64+t] + red[128+t] + red[192+t];
        float val = 0.25f*sum + bc1[t] + hc[d*320 + 256 + t] + bl1[t];
        h1[d*64 + t] = sigmoidf_(val);
    }
}

// ---------- conv2 prep ----------
__global__ void k_conv2prep(const float* __restrict__ h1, const float* __restrict__ W2c,
                            const float* __restrict__ as2, const float* __restrict__ ad2,
                            const float* __restrict__ Wl2, float* __restrict__ hh2,
                            float* __restrict__ es2, float* __restrict__ ed2,
                            float* __restrict__ lv)
{
    int i = blockIdx.x; int k = threadIdx.x; // 64
    float hv = h1[i*64 + k];
    #pragma unroll
    for (int j = 0; j < 4; ++j){
        float v = hv * W2c[k*4 + j];
        for (int m = 32; m; m >>= 1) v += __shfl_xor(v, m);
        if (k == 0){ hh2[i*4+j] = v; es2[i*4+j] = v*as2[j]; ed2[i*4+j] = v*ad2[j]; }
    }
    float v = hv * Wl2[k];
    for (int m = 32; m; m >>= 1) v += __shfl_xor(v, m);
    if (k == 0) lv[i] = v;
}

// ---------- GAT2 apply ----------
__global__ void k_gat2(const float* __restrict__ hh2, const float* __restrict__ es2,
                       const float* __restrict__ ed2, const int* __restrict__ offs,
                       const int* __restrict__ csr, const float* __restrict__ lv,
                       const float* __restrict__ bc2, const float* __restrict__ bl2,
                       float* __restrict__ feat)
{
    int d = blockIdx.x; int j = threadIdx.x; // 64
    int o = offs[d];
    int deg = offs[d+1] - o;
    int total = deg + 1;
    float edst[4];
    #pragma unroll
    for (int h = 0; h < 4; ++h) edst[h] = ed2[d*4+h];
    float lmax[4] = {-1e30f,-1e30f,-1e30f,-1e30f};
    for (int idx = j; idx < total; idx += 64){
        int s = (idx < deg) ? csr[o + idx] : d;
        #pragma unroll
        for (int h = 0; h < 4; ++h)
            lmax[h] = fmaxf(lmax[h], leakyf_(es2[s*4+h] + edst[h]));
    }
    #pragma unroll
    for (int h = 0; h < 4; ++h)
        for (int m = 32; m; m >>= 1) lmax[h] = fmaxf(lmax[h], __shfl_xor(lmax[h], m));
    float lsum[4] = {0.f,0.f,0.f,0.f};
    float lnum[4] = {0.f,0.f,0.f,0.f};
    for (int idx = j; idx < total; idx += 64){
        int s = (idx < deg) ? csr[o + idx] : d;
        #pragma unroll
        for (int h = 0; h < 4; ++h){
            float e  = leakyf_(es2[s*4+h] + edst[h]);
            float ex = __expf(e - lmax[h]);
            lsum[h] += ex;
            lnum[h] += ex * hh2[s*4+h];
        }
    }
    #pragma unroll
    for (int h = 0; h < 4; ++h){
        for (int m = 32; m; m >>= 1){ lsum[h] += __shfl_xor(lsum[h], m); lnum[h] += __shfl_xor(lnum[h], m); }
    }
    if (j == 0){
        float sum = 0.f;
        #pragma unroll
        for (int h = 0; h < 4; ++h) sum += lnum[h] / lsum[h];
        feat[d] = sigmoidf_(0.25f*sum + bc2[0] + lv[d] + bl2[0]);
    }
}

// ---------- transpose: inpT[k][row] = ctrl[row][k] + feat[k]  (k < 20000) ----------
__global__ void k_transpose(const float* __restrict__ ctrl, const float* __restrict__ feat,
                            float* __restrict__ inpT)
{
    __shared__ float tile[64][65];
    int kb = blockIdx.x, rb = blockIdx.y;
    int tx = threadIdx.x & 63, ty4 = threadIdx.x >> 6;
    int k = kb*64 + tx;
    #pragma unroll
    for (int rr = ty4; rr < 64; rr += 4){
        int row = rb*64 + rr;
        tile[rr][tx] = (k < 20000) ? ctrl[(size_t)row*20000 + k] : 0.f;
    }
    __syncthreads();
    #pragma unroll
    for (int kk = ty4; kk < 64; kk += 4){
        int kg = kb*64 + kk;
        if (kg < 20000)
            inpT[(size_t)kg*128 + rb*64 + tx] = tile[tx][kk] + feat[kg];
    }
}

// ---------- pert MLP -> writes inpT rows 20000..20063 directly ----------
__global__ void k_pert(const float* __restrict__ pert, const float* __restrict__ W1,
                       const float* __restrict__ b1, const float* __restrict__ W2,
                       const float* __restrict__ b2, float* __restrict__ inpT)
{
    int r = blockIdx.x; int t = threadIdx.x; // 128
    __shared__ float hid[128];
    float acc = 0.f;
    for (int k = 0; k < PD; ++k) acc += pert[r*PD + k] * W1[k*128 + t];
    hid[t] = sigmoidf_(acc + b1[t]);
    __syncthreads();
    if (t < 64){
        float a2 = 0.f;
        for (int k = 0; k < 128; ++k) a2 += hid[k] * W2[k*64 + t];
        inpT[(size_t)(20000 + t)*128 + r] = a2 + b2[t];
    }
}

// ---------- pred GEMM1: part[ks] = inpT[ks-chunk]^T @ W1  (no atomics) ----------
__global__ void k_gemm1(const float* __restrict__ inpT, const float* __restrict__ W1,
                        float* __restrict__ part)
{
    int t = threadIdx.x;
    int tx = t & 63, ty = t >> 6;
    int col = blockIdx.x*64 + tx;
    int ks  = blockIdx.y;
    int kbeg = ks*KCH, kend = kbeg + KCH;
    __shared__ float buf[2][1024];
    float acc[32];
    #pragma unroll
    for (int i = 0; i < 32; ++i) acc[i] = 0.f;
    int skk  = t >> 5;         // 0..7
    int srow = (t & 31) * 4;   // 0..124
    *(float4*)(&buf[0][skk*128 + srow]) =
        *(const float4*)(inpT + (size_t)(kbeg + skk)*128 + srow);
    __syncthreads();
    int b = 0;
    for (int k0 = kbeg; k0 < kend; k0 += 8, b ^= 1){
        float4 v;
        bool more = (k0 + 8) < kend;
        if (more) v = *(const float4*)(inpT + (size_t)(k0 + 8 + skk)*128 + srow);
        float w[8];
        #pragma unroll
        for (int kk = 0; kk < 8; ++kk) w[kk] = W1[(size_t)(k0+kk)*1024 + col];
        #pragma unroll
        for (int kk = 0; kk < 8; ++kk){
            #pragma unroll
            for (int i = 0; i < 32; ++i) acc[i] += buf[b][kk*128 + ty*32 + i] * w[kk];
        }
        if (more) *(float4*)(&buf[b^1][skk*128 + srow]) = v;
        __syncthreads();
    }
    float* dst = part + (size_t)ks*131072;
    #pragma unroll
    for (int i = 0; i < 32; ++i) dst[(size_t)(ty*32+i)*1024 + col] = acc[i];
}

// ---------- reduce partials + bias + sigmoid -> hidT[1024][128] ----------
__global__ void k_reduce(const float* __restrict__ part, const float* __restrict__ b1,
                         float* __restrict__ hidT)
{
    int row = blockIdx.x;                       // 0..127
    int col = blockIdx.y*256 + threadIdx.x;     // 0..1023
    float s = 0.f;
    #pragma unroll
    for (int ks = 0; ks < KSPLIT; ++ks)
        s += part[(size_t)ks*131072 + (size_t)row*1024 + col];
    hidT[(size_t)col*128 + row] = sigmoidf_(s + b1[col]);
}

// ---------- pred GEMM2: out = hidden @ pred_W2 + b2 ----------
__global__ void k_gemm2(const float* __restrict__ hidT, const float* __restrict__ W2,
                        const float* __restrict__ b2, float* __restrict__ out)
{
    int t = threadIdx.x;
    int tx = t & 63, ty = t >> 6;
    int col = blockIdx.x*64 + tx;
    bool valid = col < 20000;
    __shared__ float buf[2][1024];
    float acc[32];
    #pragma unroll
    for (int i = 0; i < 32; ++i) acc[i] = 0.f;
    int skk  = t >> 5;
    int srow = (t & 31) * 4;
    *(float4*)(&buf[0][skk*128 + srow]) =
        *(const float4*)(hidT + (size_t)skk*128 + srow);
    __syncthreads();
    int b = 0;
    for (int k0 = 0; k0 < 1024; k0 += 8, b ^= 1){
        float4 v;
        bool more = (k0 + 8) < 1024;
        if (more) v = *(const float4*)(hidT + (size_t)(k0 + 8 + skk)*128 + srow);
        float w[8];
        #pragma unroll
        for (int kk = 0; kk < 8; ++kk) w[kk] = valid ? W2[(size_t)(k0+kk)*20000 + col] : 0.f;
        #pragma unroll
        for (int kk = 0; kk < 8; ++kk){
            #pragma unroll
            for (int i = 0; i < 32; ++i) acc[i] += buf[b][kk*128 + ty*32 + i] * w[kk];
        }
        if (more) *(float4*)(&buf[b^1][skk*128 + srow]) = v;
        __syncthreads();
    }
    if (valid){
        float bb = b2[col];
        #pragma unroll
        for (int i = 0; i < 32; ++i) out[(size_t)(ty*32+i)*20000 + col] = acc[i] + bb;
    }
}

extern "C" void kernel_launch(void* const* d_in, const int* in_sizes, int n_in,
                              void* d_out, int out_size, void* d_ws, size_t ws_size,
                              hipStream_t stream)
{
    const float* x    = (const float*)d_in[0];
    const int*   ei   = (const int*)  d_in[1];
    const int*   pos  = (const int*)  d_in[2];
    const float* ctrl = (const float*)d_in[3];
    const float* pert = (const float*)d_in[4];
    const float* ge   = (const float*)d_in[5];
    const float* c1W  = (const float*)d_in[6];
    const float* c1as = (const float*)d_in[7];
    const float* c1ad = (const float*)d_in[8];
    const float* c1b  = (const float*)d_in[9];
    const float* l1W  = (const float*)d_in[10];
    const float* l1b  = (const float*)d_in[11];
    const float* c2W  = (const float*)d_in[12];
    const float* c2as = (const float*)d_in[13];
    const float* c2ad = (const float*)d_in[14];
    const float* c2b  = (const float*)d_in[15];
    const float* l2W  = (const float*)d_in[16];
    const float* l2b  = (const float*)d_in[17];
    const float* pW1  = (const float*)d_in[18];
    const float* pb1  = (const float*)d_in[19];
    const float* pW2  = (const float*)d_in[20];
    const float* pb2  = (const float*)d_in[21];
    const float* prW1 = (const float*)d_in[22];
    const float* prb1 = (const float*)d_in[23];
    const float* prW2 = (const float*)d_in[24];
    const float* prb2 = (const float*)d_in[25];
    float* out = (float*)d_out;

    char* ws = (char*)d_ws;
    size_t off = 0;
    auto alloc = [&](size_t bytes)->void*{
        void* pp = ws + off;
        off += (bytes + 255) & ~(size_t)255;
        return pp;
    };
    float* hc1  = (float*)alloc((size_t)G*320*4);      // 25.6 MB, dead after k_gat1
    float* h1   = (float*)alloc((size_t)G*64*4);
    float* es1  = (float*)alloc((size_t)G*4*4);
    float* ed1  = (float*)alloc((size_t)G*4*4);
    float* hh2  = (float*)alloc((size_t)G*4*4);
    float* es2  = (float*)alloc((size_t)G*4*4);
    float* ed2  = (float*)alloc((size_t)G*4*4);
    float* lv   = (float*)alloc((size_t)G*4);
    float* feat = (float*)alloc((size_t)G*4);
    float* hidT = (float*)alloc((size_t)1024*128*4);
    float* inpT = (float*)alloc((size_t)20064*128*4);  // 10.3 MB
    int*   cnt  = (int*)alloc((size_t)G*4);
    int*   offs = (int*)alloc((size_t)(G+1)*4);
    int*   cur  = (int*)alloc((size_t)G*4);
    int*   csr  = (int*)alloc((size_t)E_EDGES*4);
    float* part = hc1;   // alias: 33*128*1024*4 = 17.3 MB <= 25.6 MB, lifetimes disjoint

    hipMemsetAsync(cnt, 0, (size_t)G*4, stream);

    k_hist   <<<(E_EDGES+255)/256, 256, 0, stream>>>(ei, cnt);
    k_scan   <<<1, 1024, 0, stream>>>(cnt, offs);
    k_cursor <<<(G+255)/256, 256, 0, stream>>>(offs, cur);
    k_scatter<<<(E_EDGES+255)/256, 256, 0, stream>>>(ei, cur, csr);

    k_hc       <<<G, 320, 0, stream>>>(x, pos, ge, c1W, l1W, hc1);
    k_attn_coef<<<G, 256, 0, stream>>>(hc1, c1as, c1ad, es1, ed1);
    k_gat1     <<<G, 256, 0, stream>>>(hc1, es1, ed1, offs, csr, c1b, l1b, h1);
    k_conv2prep<<<G, 64, 0, stream>>>(h1, c2W, c2as, c2ad, l2W, hh2, es2, ed2, lv);
    k_gat2     <<<G, 64, 0, stream>>>(hh2, es2, ed2, offs, csr, lv, c2b, l2b, feat);

    dim3 gt(313, 2);
    k_transpose<<<gt, 256, 0, stream>>>(ctrl, feat, inpT);
    k_pert     <<<BATCH, 128, 0, stream>>>(pert, pW1, pb1, pW2, pb2, inpT);

    dim3 g1(16, KSPLIT);
    k_gemm1 <<<g1, 256, 0, stream>>>(inpT, prW1, part);
    dim3 gr(128, 4);
    k_reduce<<<gr, 256, 0, stream>>>(part, prb1, hidT);
    k_gemm2 <<<(20000+63)/64, 256, 0, stream>>>(hidT, prW2, prb2, out);
}

// Round 3
// 1026.264 us; speedup vs baseline: 8.5945x; 6.7954x over previous
//
#include <hip/hip_runtime.h>
#include <math.h>

#define G 20000
#define E_EDGES 640000
#define HID 64
#define NHEAD 4
#define BATCH 128
#define PD 600
#define NEG 0.2f
#define MAXE 1024
#define KSPLIT 33
#define KCH 608    // 33*608 = 20064, 608 % 8 == 0

__device__ __forceinline__ float sigmoidf_(float x){ return 1.0f/(1.0f+__expf(-x)); }
__device__ __forceinline__ float leakyf_(float x){ return x>=0.f ? x : NEG*x; }

// ---------- Stage 1: hc = [x | gene_embed[pos]] @ [conv1_W | lin1_W]  (G x 320) ----------
__global__ void k_hc(const float* __restrict__ x, const int* __restrict__ pos,
                     const float* __restrict__ ge, const float* __restrict__ Wc,
                     const float* __restrict__ Wl, float* __restrict__ hc)
{
    int i = blockIdx.x;
    int t = threadIdx.x; // 320 threads
    __shared__ float xc[65];
    if (t < 65) xc[t] = (t == 0) ? x[i] : ge[pos[i]*HID + (t-1)];
    __syncthreads();
    float acc = 0.f;
    if (t < 256) {
        for (int k = 0; k < 65; ++k) acc += xc[k] * Wc[k*256 + t];
    } else {
        int c = t - 256;
        for (int k = 0; k < 65; ++k) acc += xc[k] * Wl[k*64 + c];
    }
    hc[i*320 + t] = acc;
}

// ---------- e_src / e_dst for conv1 ----------
__global__ void k_attn_coef(const float* __restrict__ hc, const float* __restrict__ as_,
                            const float* __restrict__ ad_, float* __restrict__ es,
                            float* __restrict__ ed)
{
    int i = blockIdx.x; int t = threadIdx.x; // 256
    float hv = hc[i*320 + t];
    float v1 = hv * as_[t];
    float v2 = hv * ad_[t];
    for (int m = 32; m; m >>= 1) { v1 += __shfl_xor(v1, m); v2 += __shfl_xor(v2, m); }
    if ((t & 63) == 0) { int h = t >> 6; es[i*4+h] = v1; ed[i*4+h] = v2; }
}

// ---------- CSR build ----------
__global__ void k_hist(const int* __restrict__ ei, int* __restrict__ cnt){
    int e = blockIdx.x*blockDim.x + threadIdx.x;
    if (e < E_EDGES) atomicAdd(&cnt[ei[E_EDGES + e]], 1);
}
__global__ void k_scan(const int* __restrict__ cnt, int* __restrict__ offs){
    __shared__ int buf[1024];
    __shared__ int carry;
    int t = threadIdx.x;
    if (t == 0){ carry = 0; offs[0] = 0; }
    __syncthreads();
    for (int base = 0; base < G; base += 1024){
        int v = (base + t < G) ? cnt[base + t] : 0;
        buf[t] = v; __syncthreads();
        for (int off = 1; off < 1024; off <<= 1){
            int add = (t >= off) ? buf[t - off] : 0;
            __syncthreads();
            buf[t] += add;
            __syncthreads();
        }
        if (base + t < G) offs[base + t + 1] = carry + buf[t];
        __syncthreads();
        if (t == 0) carry += buf[1023];
        __syncthreads();
    }
}
__global__ void k_cursor(const int* __restrict__ offs, int* __restrict__ cur){
    int i = blockIdx.x*blockDim.x + threadIdx.x;
    if (i < G) cur[i] = offs[i];
}
__global__ void k_scatter(const int* __restrict__ ei, int* __restrict__ cur, int* __restrict__ csr){
    int e = blockIdx.x*blockDim.x + threadIdx.x;
    if (e < E_EDGES){
        int d = ei[E_EDGES + e];
        int p = atomicAdd(&cur[d], 1);
        csr[p] = ei[e];
    }
}

// ---------- GAT1 apply ----------
__global__ void k_gat1(const float* __restrict__ hc, const float* __restrict__ es,
                       const float* __restrict__ ed, const int* __restrict__ offs,
                       const int* __restrict__ csr, const float* __restrict__ bc1,
                       const float* __restrict__ bl1, float* __restrict__ h1)
{
    int d = blockIdx.x; int t = threadIdx.x; // 256
    __shared__ float cache[MAXE*4];
    __shared__ int   ssrc[MAXE];
    __shared__ float red[256];
    __shared__ float bc[8];
    int o = offs[d];
    int deg = offs[d+1] - o;
    int total = deg + 1;              // + self loop
    if (total > MAXE) total = MAXE;
    float edst[4];
    #pragma unroll
    for (int h = 0; h < 4; ++h) edst[h] = ed[d*4+h];
    float lmax[4] = {-1e30f,-1e30f,-1e30f,-1e30f};
    for (int idx = t; idx < total; idx += 256){
        int s = (idx < deg) ? csr[o + idx] : d;
        ssrc[idx] = s;
        #pragma unroll
        for (int h = 0; h < 4; ++h){
            float e = leakyf_(es[s*4+h] + edst[h]);
            cache[idx*4+h] = e;
            lmax[h] = fmaxf(lmax[h], e);
        }
    }
    __syncthreads();
    #pragma unroll
    for (int h = 0; h < 4; ++h){
        red[t] = lmax[h]; __syncthreads();
        for (int s2 = 128; s2; s2 >>= 1){ if (t < s2) red[t] = fmaxf(red[t], red[t+s2]); __syncthreads(); }
        if (t == 0) bc[h] = red[0];
        __syncthreads();
    }
    float m0 = bc[0], m1 = bc[1], m2 = bc[2], m3 = bc[3];
    float lsum[4] = {0.f,0.f,0.f,0.f};
    for (int idx = t; idx < total; idx += 256){
        float e0 = __expf(cache[idx*4+0] - m0); cache[idx*4+0] = e0; lsum[0] += e0;
        float e1 = __expf(cache[idx*4+1] - m1); cache[idx*4+1] = e1; lsum[1] += e1;
        float e2 = __expf(cache[idx*4+2] - m2); cache[idx*4+2] = e2; lsum[2] += e2;
        float e3 = __expf(cache[idx*4+3] - m3); cache[idx*4+3] = e3; lsum[3] += e3;
    }
    __syncthreads();
    #pragma unroll
    for (int h = 0; h < 4; ++h){
        red[t] = lsum[h]; __syncthreads();
        for (int s2 = 128; s2; s2 >>= 1){ if (t < s2) red[t] += red[t+s2]; __syncthreads(); }
        if (t == 0) bc[4+h] = 1.0f / red[0];
        __syncthreads();
    }
    int h = t >> 6, c = t & 63;
    float inv = bc[4+h];
    float acc = 0.f;
    for (int idx = 0; idx < total; ++idx){
        int s = ssrc[idx];
        float alpha = cache[idx*4+h] * inv;
        acc += alpha * hc[s*320 + h*64 + c];
    }
    red[t] = acc;
    __syncthreads();
    if (t < 64){
        float sum = red[t] + red[64+t] + red[128+t] + red[192+t];
        float val = 0.25f*sum + bc1[t] + hc[d*320 + 256 + t] + bl1[t];
        h1[d*64 + t] = sigmoidf_(val);
    }
}

// ---------- conv2 prep ----------
__global__ void k_conv2prep(const float* __restrict__ h1, const float* __restrict__ W2c,
                            const float* __restrict__ as2, const float* __restrict__ ad2,
                            const float* __restrict__ Wl2, float* __restrict__ hh2,
                            float* __restrict__ es2, float* __restrict__ ed2,
                            float* __restrict__ lv)
{
    int i = blockIdx.x; int k = threadIdx.x; // 64
    float hv = h1[i*64 + k];
    #pragma unroll
    for (int j = 0; j < 4; ++j){
        float v = hv * W2c[k*4 + j];
        for (int m = 32; m; m >>= 1) v += __shfl_xor(v, m);
        if (k == 0){ hh2[i*4+j] = v; es2[i*4+j] = v*as2[j]; ed2[i*4+j] = v*ad2[j]; }
    }
    float v = hv * Wl2[k];
    for (int m = 32; m; m >>= 1) v += __shfl_xor(v, m);
    if (k == 0) lv[i] = v;
}

// ---------- GAT2 apply ----------
__global__ void k_gat2(const float* __restrict__ hh2, const float* __restrict__ es2,
                       const float* __restrict__ ed2, const int* __restrict__ offs,
                       const int* __restrict__ csr, const float* __restrict__ lv,
                       const float* __restrict__ bc2, const float* __restrict__ bl2,
                       float* __restrict__ feat)
{
    int d = blockIdx.x; int j = threadIdx.x; // 64
    int o = offs[d];
    int deg = offs[d+1] - o;
    int total = deg + 1;
    float edst[4];
    #pragma unroll
    for (int h = 0; h < 4; ++h) edst[h] = ed2[d*4+h];
    float lmax[4] = {-1e30f,-1e30f,-1e30f,-1e30f};
    for (int idx = j; idx < total; idx += 64){
        int s = (idx < deg) ? csr[o + idx] : d;
        #pragma unroll
        for (int h = 0; h < 4; ++h)
            lmax[h] = fmaxf(lmax[h], leakyf_(es2[s*4+h] + edst[h]));
    }
    #pragma unroll
    for (int h = 0; h < 4; ++h)
        for (int m = 32; m; m >>= 1) lmax[h] = fmaxf(lmax[h], __shfl_xor(lmax[h], m));
    float lsum[4] = {0.f,0.f,0.f,0.f};
    float lnum[4] = {0.f,0.f,0.f,0.f};
    for (int idx = j; idx < total; idx += 64){
        int s = (idx < deg) ? csr[o + idx] : d;
        #pragma unroll
        for (int h = 0; h < 4; ++h){
            float e  = leakyf_(es2[s*4+h] + edst[h]);
            float ex = __expf(e - lmax[h]);
            lsum[h] += ex;
            lnum[h] += ex * hh2[s*4+h];
        }
    }
    #pragma unroll
    for (int h = 0; h < 4; ++h){
        for (int m = 32; m; m >>= 1){ lsum[h] += __shfl_xor(lsum[h], m); lnum[h] += __shfl_xor(lnum[h], m); }
    }
    if (j == 0){
        float sum = 0.f;
        #pragma unroll
        for (int h = 0; h < 4; ++h) sum += lnum[h] / lsum[h];
        feat[d] = sigmoidf_(0.25f*sum + bc2[0] + lv[d] + bl2[0]);
    }
}

// ---------- transpose: inpT[k][row] = ctrl[row][k] + feat[k]  (k < 20000) ----------
__global__ void k_transpose(const float* __restrict__ ctrl, const float* __restrict__ feat,
                            float* __restrict__ inpT)
{
    __shared__ float tile[64][65];
    int kb = blockIdx.x, rb = blockIdx.y;
    int tx = threadIdx.x & 63, ty4 = threadIdx.x >> 6;
    int k = kb*64 + tx;
    #pragma unroll
    for (int rr = ty4; rr < 64; rr += 4){
        int row = rb*64 + rr;
        tile[rr][tx] = (k < 20000) ? ctrl[(size_t)row*20000 + k] : 0.f;
    }
    __syncthreads();
    #pragma unroll
    for (int kk = ty4; kk < 64; kk += 4){
        int kg = kb*64 + kk;
        if (kg < 20000)
            inpT[(size_t)kg*128 + rb*64 + tx] = tile[tx][kk] + feat[kg];
    }
}

// ---------- pert MLP -> writes inpT rows 20000..20063 directly ----------
__global__ void k_pert(const float* __restrict__ pert, const float* __restrict__ W1,
                       const float* __restrict__ b1, const float* __restrict__ W2,
                       const float* __restrict__ b2, float* __restrict__ inpT)
{
    int r = blockIdx.x; int t = threadIdx.x; // 128
    __shared__ float hid[128];
    float acc = 0.f;
    for (int k = 0; k < PD; ++k) acc += pert[r*PD + k] * W1[k*128 + t];
    hid[t] = sigmoidf_(acc + b1[t]);
    __syncthreads();
    if (t < 64){
        float a2 = 0.f;
        for (int k = 0; k < 128; ++k) a2 += hid[k] * W2[k*64 + t];
        inpT[(size_t)(20000 + t)*128 + r] = a2 + b2[t];
    }
}

// ---------- pred GEMM1: part[ks] = inpT-chunk^T @ W1, 64-row x 64-col tile ----------
// grid (16, KSPLIT, 2); acc[16]/thread; __launch_bounds__ 128-VGPR budget -> no spill
__global__ __launch_bounds__(256, 2)
void k_gemm1(const float* __restrict__ inpT, const float* __restrict__ W1,
             float* __restrict__ part)
{
    int t = threadIdx.x;
    int tx = t & 63, ty = t >> 6;            // ty 0..3
    int col   = blockIdx.x*64 + tx;
    int ks    = blockIdx.y;
    int rbase = blockIdx.z << 6;             // 0 or 64
    int kbeg = ks*KCH, kend = kbeg + KCH;
    __shared__ float buf[2][512];            // 8 k x 64 rows
    float acc[16];
    #pragma unroll
    for (int i = 0; i < 16; ++i) acc[i] = 0.f;
    int skk  = t >> 4;                       // 0..7 (loaders only)
    int srow = (t & 15) * 4;                 // 0..60
    bool loader = t < 128;
    if (loader)
        *(float4*)(&buf[0][skk*64 + srow]) =
            *(const float4*)(inpT + (size_t)(kbeg + skk)*128 + rbase + srow);
    __syncthreads();
    int b = 0;
    for (int k0 = kbeg; k0 < kend; k0 += 8, b ^= 1){
        float4 v;
        bool more = (k0 + 8) < kend;
        if (loader && more)
            v = *(const float4*)(inpT + (size_t)(k0 + 8 + skk)*128 + rbase + srow);
        #pragma unroll
        for (int kk = 0; kk < 8; ++kk){
            float w = W1[(size_t)(k0+kk)*1024 + col];
            #pragma unroll
            for (int i = 0; i < 16; ++i) acc[i] += buf[b][kk*64 + ty*16 + i] * w;
        }
        if (loader && more) *(float4*)(&buf[b^1][skk*64 + srow]) = v;
        __syncthreads();
    }
    float* dst = part + (size_t)ks*131072;
    #pragma unroll
    for (int i = 0; i < 16; ++i) dst[(size_t)(rbase + ty*16 + i)*1024 + col] = acc[i];
}

// ---------- reduce partials + bias + sigmoid -> hidT[1024][128] ----------
__global__ void k_reduce(const float* __restrict__ part, const float* __restrict__ b1,
                         float* __restrict__ hidT)
{
    int row = blockIdx.x;                       // 0..127
    int col = blockIdx.y*256 + threadIdx.x;     // 0..1023
    float s = 0.f;
    #pragma unroll
    for (int ks = 0; ks < KSPLIT; ++ks)
        s += part[(size_t)ks*131072 + (size_t)row*1024 + col];
    hidT[(size_t)col*128 + row] = sigmoidf_(s + b1[col]);
}

// ---------- pred GEMM2: out = hidden @ pred_W2 + b2, 64-row x 64-col tile ----------
// grid (313, 2)
__global__ __launch_bounds__(256, 2)
void k_gemm2(const float* __restrict__ hidT, const float* __restrict__ W2,
             const float* __restrict__ b2, float* __restrict__ out)
{
    int t = threadIdx.x;
    int tx = t & 63, ty = t >> 6;
    int col   = blockIdx.x*64 + tx;
    int rbase = blockIdx.y << 6;
    bool valid = col < 20000;
    __shared__ float buf[2][512];
    float acc[16];
    #pragma unroll
    for (int i = 0; i < 16; ++i) acc[i] = 0.f;
    int skk  = t >> 4;
    int srow = (t & 15) * 4;
    bool loader = t < 128;
    if (loader)
        *(float4*)(&buf[0][skk*64 + srow]) =
            *(const float4*)(hidT + (size_t)skk*128 + rbase + srow);
    __syncthreads();
    int b = 0;
    for (int k0 = 0; k0 < 1024; k0 += 8, b ^= 1){
        float4 v;
        bool more = (k0 + 8) < 1024;
        if (loader && more)
            v = *(const float4*)(hidT + (size_t)(k0 + 8 + skk)*128 + rbase + srow);
        #pragma unroll
        for (int kk = 0; kk < 8; ++kk){
            float w = valid ? W2[(size_t)(k0+kk)*20000 + col] : 0.f;
            #pragma unroll
            for (int i = 0; i < 16; ++i) acc[i] += buf[b][kk*64 + ty*16 + i] * w;
        }
        if (loader && more) *(float4*)(&buf[b^1][skk*64 + srow]) = v;
        __syncthreads();
    }
    if (valid){
        float bb = b2[col];
        #pragma unroll
        for (int i = 0; i < 16; ++i)
            out[(size_t)(rbase + ty*16 + i)*20000 + col] = acc[i] + bb;
    }
}

extern "C" void kernel_launch(void* const* d_in, const int* in_sizes, int n_in,
                              void* d_out, int out_size, void* d_ws, size_t ws_size,
                              hipStream_t stream)
{
    const float* x    = (const float*)d_in[0];
    const int*   ei   = (const int*)  d_in[1];
    const int*   pos  = (const int*)  d_in[2];
    const float* ctrl = (const float*)d_in[3];
    const float* pert = (const float*)d_in[4];
    const float* ge   = (const float*)d_in[5];
    const float* c1W  = (const float*)d_in[6];
    const float* c1as = (const float*)d_in[7];
    const float* c1ad = (const float*)d_in[8];
    const float* c1b  = (const float*)d_in[9];
    const float* l1W  = (const float*)d_in[10];
    const float* l1b  = (const float*)d_in[11];
    const float* c2W  = (const float*)d_in[12];
    const float* c2as = (const float*)d_in[13];
    const float* c2ad = (const float*)d_in[14];
    const float* c2b  = (const float*)d_in[15];
    const float* l2W  = (const float*)d_in[16];
    const float* l2b  = (const float*)d_in[17];
    const float* pW1  = (const float*)d_in[18];
    const float* pb1  = (const float*)d_in[19];
    const float* pW2  = (const float*)d_in[20];
    const float* pb2  = (const float*)d_in[21];
    const float* prW1 = (const float*)d_in[22];
    const float* prb1 = (const float*)d_in[23];
    const float* prW2 = (const float*)d_in[24];
    const float* prb2 = (const float*)d_in[25];
    float* out = (float*)d_out;

    char* ws = (char*)d_ws;
    size_t off = 0;
    auto alloc = [&](size_t bytes)->void*{
        void* pp = ws + off;
        off += (bytes + 255) & ~(size_t)255;
        return pp;
    };
    float* hc1  = (float*)alloc((size_t)G*320*4);      // 25.6 MB, dead after k_gat1
    float* h1   = (float*)alloc((size_t)G*64*4);
    float* es1  = (float*)alloc((size_t)G*4*4);
    float* ed1  = (float*)alloc((size_t)G*4*4);
    float* hh2  = (float*)alloc((size_t)G*4*4);
    float* es2  = (float*)alloc((size_t)G*4*4);
    float* ed2  = (float*)alloc((size_t)G*4*4);
    float* lv   = (float*)alloc((size_t)G*4);
    float* feat = (float*)alloc((size_t)G*4);
    float* hidT = (float*)alloc((size_t)1024*128*4);
    float* inpT = (float*)alloc((size_t)20064*128*4);  // 10.3 MB
    int*   cnt  = (int*)alloc((size_t)G*4);
    int*   offs = (int*)alloc((size_t)(G+1)*4);
    int*   cur  = (int*)alloc((size_t)G*4);
    int*   csr  = (int*)alloc((size_t)E_EDGES*4);
    float* part = hc1;   // alias: 33*128*1024*4 = 17.3 MB <= 25.6 MB, lifetimes disjoint

    hipMemsetAsync(cnt, 0, (size_t)G*4, stream);

    k_hist   <<<(E_EDGES+255)/256, 256, 0, stream>>>(ei, cnt);
    k_scan   <<<1, 1024, 0, stream>>>(cnt, offs);
    k_cursor <<<(G+255)/256, 256, 0, stream>>>(offs, cur);
    k_scatter<<<(E_EDGES+255)/256, 256, 0, stream>>>(ei, cur, csr);

    k_hc       <<<G, 320, 0, stream>>>(x, pos, ge, c1W, l1W, hc1);
    k_attn_coef<<<G, 256, 0, stream>>>(hc1, c1as, c1ad, es1, ed1);
    k_gat1     <<<G, 256, 0, stream>>>(hc1, es1, ed1, offs, csr, c1b, l1b, h1);
    k_conv2prep<<<G, 64, 0, stream>>>(h1, c2W, c2as, c2ad, l2W, hh2, es2, ed2, lv);
    k_gat2     <<<G, 64, 0, stream>>>(hh2, es2, ed2, offs, csr, lv, c2b, l2b, feat);

    dim3 gt(313, 2);
    k_transpose<<<gt, 256, 0, stream>>>(ctrl, feat, inpT);
    k_pert     <<<BATCH, 128, 0, stream>>>(pert, pW1, pb1, pW2, pb2, inpT);

    dim3 g1(16, KSPLIT, 2);
    k_gemm1 <<<g1, 256, 0, stream>>>(inpT, prW1, part);
    dim3 gr(128, 4);
    k_reduce<<<gr, 256, 0, stream>>>(part, prb1, hidT);
    dim3 g2(313, 2);
    k_gemm2 <<<g2, 256, 0, stream>>>(hidT, prW2, prb2, out);
}